// Round 3
// baseline (2218.693 us; speedup 1.0000x reference)
//
#include <hip/hip_runtime.h>
#include <hip/hip_bf16.h>
#include <math.h>

typedef float f32x4 __attribute__((ext_vector_type(4)));
typedef short s16x8 __attribute__((ext_vector_type(8)));
typedef float v2f   __attribute__((ext_vector_type(2)));

// ---- workspace layout (bytes) ---- total < 1 MB
static const long long OFF_W2  = 0LL;        // bf16 [9][128][64]  = 147,456 B
static const long long OFF_W3  = 147456LL;   // bf16 [9][256][128] = 589,824 B
static const long long OFF_AB1 = 737280LL;   // float2 [64]
static const long long OFF_AB2 = 737792LL;   // float2 [128]
static const long long OFF_AB3 = 738816LL;   // float2 [256]
static const long long OFF_Q   = 740864LL;   // float  [8]

__device__ inline unsigned short f2bfu(float f) {
    __hip_bfloat16 h = __float2bfloat16(f);
    unsigned short u;
    __builtin_memcpy(&u, &h, 2);
    return u;
}

// ---------------- prep: weight transpose to [kykx][oc][ic] bf16 + BN folding + fc fold ----------------
__global__ __launch_bounds__(256) void prep_k(
    const float* __restrict__ c2w, const float* __restrict__ c3w,
    const float* __restrict__ c1b, const float* __restrict__ g1, const float* __restrict__ b1,
    const float* __restrict__ m1, const float* __restrict__ v1,
    const float* __restrict__ c2b, const float* __restrict__ g2, const float* __restrict__ b2,
    const float* __restrict__ m2, const float* __restrict__ v2,
    const float* __restrict__ c3b, const float* __restrict__ g3, const float* __restrict__ b3,
    const float* __restrict__ m3, const float* __restrict__ v3,
    const float* __restrict__ fc1b, const float* __restrict__ qp,
    const float* __restrict__ fc2w, const float* __restrict__ fc2b,
    const float* __restrict__ fc3w, const float* __restrict__ fc3b,
    short* __restrict__ wT2, short* __restrict__ wT3,
    float2* __restrict__ ab1, float2* __restrict__ ab2, float2* __restrict__ ab3,
    float* __restrict__ qc)
{
    int tid = blockIdx.x * 256 + threadIdx.x;
    if (tid < 73728) {                       // 9*128*64
        int ic = tid & 63, oc = (tid >> 6) & 127, k = tid >> 13;
        wT2[tid] = (short)f2bfu(c2w[(oc * 64 + ic) * 9 + k]);
    }
    if (tid < 294912) {                      // 9*256*128
        int ic = tid & 127, oc = (tid >> 7) & 255, k = tid >> 15;
        wT3[tid] = (short)f2bfu(c3w[(oc * 128 + ic) * 9 + k]);
    }
    if (tid < 64) {
        float s = g1[tid] / sqrtf(v1[tid] + 1e-5f);
        ab1[tid] = make_float2(s, (c1b[tid] - m1[tid]) * s + b1[tid]);
    } else if (tid < 192) {
        int c = tid - 64;
        float s = g2[c] / sqrtf(v2[c] + 1e-5f);
        ab2[c] = make_float2(s, (c2b[c] - m2[c]) * s + b2[c]);
    } else if (tid < 448) {
        int c = tid - 192;
        float s = g3[c] / sqrtf(v3[c] + 1e-5f);
        ab3[c] = make_float2(s, (c3b[c] - m3[c]) * s + b3[c]);
    } else if (tid == 448) {
        float A0 = 0.f, A1 = 0.f, B0 = 0.f, B1 = 0.f;
        for (int k = 0; k < 128; ++k) {
            float f2 = fc2w[k], fb = fc2b[k];
            A0 += fc3w[k] * f2;        B0 += fc3w[k] * fb;
            A1 += fc3w[128 + k] * f2;  B1 += fc3w[128 + k] * fb;
        }
        qc[0] = A0; qc[1] = A1;
        qc[2] = B0 + fc3b[0]; qc[3] = B1 + fc3b[1];
        qc[4] = cosf(qp[1]);  qc[5] = fc1b[1];
    }
}

// ---------------- fused: conv1 -> conv2(MFMA) -> conv3(MFMA) -> tail. One block per image. ----------------
// LDS: smem holds conv2 input tile (33,024 B incl. OOB pad); conv3 tile ALIASES smem (re-zeroed
// between barriers after conv2's MFMA loop finishes reading). xt = padded 28x28 fp32 input.
__global__ __launch_bounds__(256, 3) void fused_k(
    const float* __restrict__ x, const float* __restrict__ c1w,
    const float2* __restrict__ ab1, const float2* __restrict__ ab2,
    const float2* __restrict__ ab3,
    const short* __restrict__ wT2, const short* __restrict__ wT3,
    const float* __restrict__ fc1w, const float* __restrict__ qc,
    float* __restrict__ out)
{
    __shared__ short smem[16 * 16 * 64 + 128]; // conv2 tile [y][x][8 blk][8 ic] swizzled + pad (33,024 B)
    __shared__ float xt[30][32];               // padded 28x28 input at [1..28][1..28]      (3,840 B)
    __shared__ float red[4];

    int b = blockIdx.x, t = threadIdx.x;

    // ---- zero-init (padding must be 0) ----
    for (int i = t; i < 8256; i += 256) ((unsigned*)smem)[i] = 0u;
    for (int i = t; i < 960;  i += 256) ((float*)xt)[i] = 0.f;
    __syncthreads();

    // ---- stage A: load input, conv1 (packed fp32) + BN + ReLU + 2x2 pool -> smem (conv2 tile) ----
    for (int i = t; i < 784; i += 256) xt[i / 28 + 1][i % 28 + 1] = x[b * 784 + i];

    int ocg = t & 7;                         // 8 groups of 8 output channels
    float wr[8][9];
    float2 abr[8];
#pragma unroll
    for (int c = 0; c < 8; ++c) {
#pragma unroll
        for (int k = 0; k < 9; ++k) wr[c][k] = c1w[(ocg * 8 + c) * 9 + k];
        abr[c] = ab1[ocg * 8 + c];
    }
    __syncthreads();

    int posb = t >> 3;                       // 0..31
    for (int p = posb; p < 196; p += 32) {
        int py = p / 14, px = p % 14;
        int y0 = 2 * py, x0 = 2 * px;        // x0 even -> 8B-aligned v2f loads
        v2f rowv[4][2];
#pragma unroll
        for (int i = 0; i < 4; ++i) {
            rowv[i][0] = *(const v2f*)&xt[y0 + i][x0];
            rowv[i][1] = *(const v2f*)&xt[y0 + i][x0 + 2];
        }
        unsigned short ub[8];
#pragma unroll
        for (int c = 0; c < 8; ++c) {
            v2f a0 = {0.f, 0.f}, a1 = {0.f, 0.f};   // (out00,out01), (out10,out11)
#pragma unroll
            for (int ky = 0; ky < 3; ++ky) {
                float w0 = wr[c][ky * 3 + 0], w1 = wr[c][ky * 3 + 1], w2 = wr[c][ky * 3 + 2];
                v2f p00 = rowv[ky][0],     p01 = rowv[ky][1];
                v2f p10 = rowv[ky + 1][0], p11 = rowv[ky + 1][1];
                v2f q0; q0.x = p00.y; q0.y = p01.x;
                v2f q1; q1.x = p10.y; q1.y = p11.x;
                a0 += p00 * w0; a0 += q0 * w1; a0 += p01 * w2;
                a1 += p10 * w0; a1 += q1 * w1; a1 += p11 * w2;
            }
            float aa = abr[c].x, bb = abr[c].y;
            v2f r0 = a0 * aa + bb;
            v2f r1 = a1 * aa + bb;
            float v = fmaxf(fmaxf(fmaxf(r0.x, r0.y), fmaxf(r1.x, r1.y)), 0.f);
            ub[c] = f2bfu(v);
        }
        uint4 pk;
        pk.x = (unsigned)ub[0] | ((unsigned)ub[1] << 16);
        pk.y = (unsigned)ub[2] | ((unsigned)ub[3] << 16);
        pk.z = (unsigned)ub[4] | ((unsigned)ub[5] << 16);
        pk.w = (unsigned)ub[6] | ((unsigned)ub[7] << 16);
        int blk = ocg ^ ((px + 1) & 7);      // XOR swizzle by padded column
        *(uint4*)&smem[((((py + 1) * 16) + (px + 1)) * 8 + blk) * 8] = pk;
    }
    __syncthreads();

    // ---- stage B: conv2 (64->128) MFMA. Waves: (oc-half oh) x (pooled-col-half cb). ----
    int lane = t & 63, wid = t >> 6;
    int quad = lane >> 4, n16 = lane & 15;
    int dy = n16 >> 3, lx = n16 & 7;
    int cb = wid >> 1;                       // 0: output cols 1..8 ; 1: cols 9..16
    int oh = wid & 1;                        // oc half (64 ocs)

    {
        f32x4 acc[4][7];                     // [ml(16oc)][ry(pooled row)]
        f32x4 z = {0.f, 0.f, 0.f, 0.f};
#pragma unroll
        for (int ml = 0; ml < 4; ++ml)
#pragma unroll
            for (int ry = 0; ry < 7; ++ry) acc[ml][ry] = z;

#pragma unroll 1
        for (int kykx = 0; kykx < 9; ++kykx) {
            int ky = kykx / 3, kx = kykx - 3 * ky;
            int y0 = dy + ky;
            int xc = lx + kx + cb * 8;       // padded input col (garbage lanes lx>=6@cb=1 discarded)
            const short* aB = wT2 + (kykx * 128 + oh * 64 + n16) * 64 + quad * 8;
#pragma unroll
            for (int kk = 0; kk < 2; ++kk) {
                int blk = (kk * 4 + quad) ^ (xc & 7);
                const short* bp = &smem[((y0 * 16 + xc) * 8 + blk) * 8];
                s16x8 A[4];
#pragma unroll
                for (int ml = 0; ml < 4; ++ml)
                    A[ml] = *(const s16x8*)(aB + ml * 1024 + kk * 32);
#pragma unroll
                for (int ry = 0; ry < 7; ++ry) {
                    s16x8 B = *(const s16x8*)(bp + ry * 2048);   // immediate offsets
#pragma unroll
                    for (int ml = 0; ml < 4; ++ml)
                        acc[ml][ry] = __builtin_amdgcn_mfma_f32_16x16x32_bf16(A[ml], B, acc[ml][ry], 0, 0, 0);
                }
            }
        }

        __syncthreads();                     // all waves done reading conv2 tile
        for (int i = t; i < 4224; i += 256) ((unsigned*)smem)[i] = 0u;  // zero conv3 tile (alias)
        __syncthreads();

        // epilogue: affine -> pool (shfl 1,8) -> ReLU -> store into conv3 tile (swizzled)
        int m = lx >> 1;
        int xp = cb * 4 + m;
        bool keep = (dy == 0) && ((lx & 1) == 0) && (xp < 7);
#pragma unroll
        for (int ml = 0; ml < 4; ++ml) {
            int oc0 = oh * 64 + ml * 16 + quad * 4;
            float2 abv[4];
#pragma unroll
            for (int r = 0; r < 4; ++r) abv[r] = ab2[oc0 + r];
#pragma unroll
            for (int ry = 0; ry < 7; ++ry) {
                float pv[4];
#pragma unroll
                for (int r = 0; r < 4; ++r) {
                    float v = acc[ml][ry][r] * abv[r].x + abv[r].y;
                    v = fmaxf(v, __shfl_xor(v, 1));
                    v = fmaxf(v, __shfl_xor(v, 8));
                    pv[r] = fmaxf(v, 0.f);
                }
                if (keep) {
                    uint2 pk;
                    pk.x = (unsigned)f2bfu(pv[0]) | ((unsigned)f2bfu(pv[1]) << 16);
                    pk.y = (unsigned)f2bfu(pv[2]) | ((unsigned)f2bfu(pv[3]) << 16);
                    int blk3 = (oc0 >> 3) ^ (((xp + 1) & 7) << 1);
                    *(uint2*)&smem[(((ry + 1) * 8 + (xp + 1)) * 16 + blk3) * 8 + (oc0 & 7)] = pk;
                }
            }
        }
    }
    __syncthreads();

    // ---- stage C: conv3 (128->256) MFMA. Waves: (oc-half oh3) x (nt group nth). ----
    int oh3 = wid & 1;                       // oc half (128 ocs, 8 frags)
    int nth = wid >> 1;                      // 0: pooled rows {0,1} ; 1: {2}

    f32x4 acc3[8][2];
    {
        f32x4 z = {0.f, 0.f, 0.f, 0.f};
#pragma unroll
        for (int ml = 0; ml < 8; ++ml) { acc3[ml][0] = z; acc3[ml][1] = z; }
    }

    if (nth == 0) {
#pragma unroll 1
        for (int kykx = 0; kykx < 9; ++kykx) {
            int ky = kykx / 3, kx = kykx - 3 * ky;
            int y0 = dy + ky;
            int x0 = lx + kx;                // garbage lanes lx>=6 discarded
            const short* aB = wT3 + (kykx * 256 + oh3 * 128 + n16) * 128 + quad * 8;
#pragma unroll
            for (int kk = 0; kk < 4; ++kk) {
                int blk = (kk * 4 + quad) ^ ((x0 & 7) << 1);
                const short* bp = &smem[((y0 * 8 + x0) * 16 + blk) * 8];
                s16x8 B0 = *(const s16x8*)(bp);
                s16x8 B1 = *(const s16x8*)(bp + 2048);
#pragma unroll
                for (int ml = 0; ml < 8; ++ml) {
                    s16x8 A = *(const s16x8*)(aB + ml * 2048 + kk * 32);
                    acc3[ml][0] = __builtin_amdgcn_mfma_f32_16x16x32_bf16(A, B0, acc3[ml][0], 0, 0, 0);
                    acc3[ml][1] = __builtin_amdgcn_mfma_f32_16x16x32_bf16(A, B1, acc3[ml][1], 0, 0, 0);
                }
            }
        }
    } else {
#pragma unroll 1
        for (int kykx = 0; kykx < 9; ++kykx) {
            int ky = kykx / 3, kx = kykx - 3 * ky;
            int y0 = dy + ky;
            int x0 = lx + kx;
            const short* aB = wT3 + (kykx * 256 + oh3 * 128 + n16) * 128 + quad * 8;
#pragma unroll
            for (int kk = 0; kk < 4; ++kk) {
                int blk = (kk * 4 + quad) ^ ((x0 & 7) << 1);
                const short* bp = &smem[((y0 * 8 + x0) * 16 + blk) * 8 + 4096];  // rows y_in = 4+..
                s16x8 B0 = *(const s16x8*)(bp);
#pragma unroll
                for (int ml = 0; ml < 8; ++ml) {
                    s16x8 A = *(const s16x8*)(aB + ml * 2048 + kk * 32);
                    acc3[ml][0] = __builtin_amdgcn_mfma_f32_16x16x32_bf16(A, B0, acc3[ml][0], 0, 0, 0);
                }
            }
        }
    }

    // epilogue: affine -> pool -> relu -> dot with fc1_w row 1
    float vacc = 0.f;
    {
        int m = lx >> 1;
        bool keep = (dy == 0) && ((lx & 1) == 0) && (m < 3);
        const float* fc1w1 = fc1w + 2304;    // row 1 (only row that matters)
        int ntCount = (nth == 0) ? 2 : 1;
#pragma unroll
        for (int ml = 0; ml < 8; ++ml) {
            int oc0 = oh3 * 128 + ml * 16 + quad * 4;
            float2 abv[4];
#pragma unroll
            for (int r = 0; r < 4; ++r) abv[r] = ab3[oc0 + r];
            for (int ntl = 0; ntl < ntCount; ++ntl) {
                int nt = nth * 2 + ntl;      // pooled row
#pragma unroll
                for (int r = 0; r < 4; ++r) {
                    float v = acc3[ml][ntl][r] * abv[r].x + abv[r].y;
                    v = fmaxf(v, __shfl_xor(v, 1));
                    v = fmaxf(v, __shfl_xor(v, 8));
                    v = fmaxf(v, 0.f);
                    if (keep) vacc += v * fc1w1[(oc0 + r) * 9 + nt * 3 + m];
                }
            }
        }
    }
#pragma unroll
    for (int s = 1; s < 64; s <<= 1) vacc += __shfl_xor(vacc, s);
    if (lane == 0) red[wid] = vacc;
    __syncthreads();
    if (t == 0) {
        float v = red[0] + red[1] + red[2] + red[3] + qc[5];
        // quantum circuit closed form: <Z0 Z1> = cos(h[:,1]) * cos(qp[1])
        float q = cosf(v) * qc[4];
        float l0 = q * qc[0] + qc[2];
        float l1 = q * qc[1] + qc[3];
        float mx = fmaxf(l0, l1);
        float lse = mx + logf(__expf(l0 - mx) + __expf(l1 - mx));
        out[b * 2 + 0] = l0 - lse;
        out[b * 2 + 1] = l1 - lse;
    }
}

extern "C" void kernel_launch(void* const* d_in, const int* in_sizes, int n_in,
                              void* d_out, int out_size, void* d_ws, size_t ws_size,
                              hipStream_t stream)
{
    const float* x    = (const float*)d_in[0];
    const float* c1w  = (const float*)d_in[1];
    const float* c1b  = (const float*)d_in[2];
    const float* c2w  = (const float*)d_in[3];
    const float* c2b  = (const float*)d_in[4];
    const float* c3w  = (const float*)d_in[5];
    const float* c3b  = (const float*)d_in[6];
    const float* g1   = (const float*)d_in[7];
    const float* b1   = (const float*)d_in[8];
    const float* m1   = (const float*)d_in[9];
    const float* v1   = (const float*)d_in[10];
    const float* g2   = (const float*)d_in[11];
    const float* b2   = (const float*)d_in[12];
    const float* m2   = (const float*)d_in[13];
    const float* v2   = (const float*)d_in[14];
    const float* g3   = (const float*)d_in[15];
    const float* b3   = (const float*)d_in[16];
    const float* m3   = (const float*)d_in[17];
    const float* v3   = (const float*)d_in[18];
    const float* fc1w = (const float*)d_in[19];
    const float* fc1b = (const float*)d_in[20];
    const float* qp   = (const float*)d_in[21];
    const float* fc2w = (const float*)d_in[22];
    const float* fc2b = (const float*)d_in[23];
    const float* fc3w = (const float*)d_in[24];
    const float* fc3b = (const float*)d_in[25];
    float* out = (float*)d_out;
    char* ws = (char*)d_ws;

    short*  wT2 = (short*)(ws + OFF_W2);
    short*  wT3 = (short*)(ws + OFF_W3);
    float2* ab1 = (float2*)(ws + OFF_AB1);
    float2* ab2 = (float2*)(ws + OFF_AB2);
    float2* ab3 = (float2*)(ws + OFF_AB3);
    float*  qc  = (float*)(ws + OFF_Q);

    int B = in_sizes[0] / 784;               // 8192

    prep_k<<<1152, 256, 0, stream>>>(c2w, c3w, c1b, g1, b1, m1, v1,
                                     c2b, g2, b2, m2, v2, c3b, g3, b3, m3, v3,
                                     fc1b, qp, fc2w, fc2b, fc3w, fc3b,
                                     wT2, wT3, ab1, ab2, ab3, qc);
    fused_k<<<B, 256, 0, stream>>>(x, c1w, ab1, ab2, ab3, wT2, wT3, fc1w, qc, out);
}

// Round 4
// 1771.533 us; speedup vs baseline: 1.2524x; 1.2524x over previous
//
#include <hip/hip_runtime.h>
#include <hip/hip_bf16.h>
#include <math.h>

typedef float f32x4 __attribute__((ext_vector_type(4)));
typedef short s16x8 __attribute__((ext_vector_type(8)));
typedef float v2f   __attribute__((ext_vector_type(2)));

// ---- workspace layout (bytes) ---- total < 1 MB
static const long long OFF_W2  = 0LL;        // bf16 [9][128][64]  = 147,456 B
static const long long OFF_W3  = 147456LL;   // bf16 [9][256][128] = 589,824 B
static const long long OFF_AB1 = 737280LL;   // float2 [64]
static const long long OFF_AB2 = 737792LL;   // float2 [128]
static const long long OFF_AB3 = 738816LL;   // float2 [256]
static const long long OFF_Q   = 740864LL;   // float  [8]

__device__ inline unsigned short f2bfu(float f) {
    __hip_bfloat16 h = __float2bfloat16(f);
    unsigned short u;
    __builtin_memcpy(&u, &h, 2);
    return u;
}

// ---------------- prep: weight transpose to [kykx][oc][ic] bf16 + BN folding + fc fold ----------------
__global__ __launch_bounds__(256) void prep_k(
    const float* __restrict__ c2w, const float* __restrict__ c3w,
    const float* __restrict__ c1b, const float* __restrict__ g1, const float* __restrict__ b1,
    const float* __restrict__ m1, const float* __restrict__ v1,
    const float* __restrict__ c2b, const float* __restrict__ g2, const float* __restrict__ b2,
    const float* __restrict__ m2, const float* __restrict__ v2,
    const float* __restrict__ c3b, const float* __restrict__ g3, const float* __restrict__ b3,
    const float* __restrict__ m3, const float* __restrict__ v3,
    const float* __restrict__ fc1b, const float* __restrict__ qp,
    const float* __restrict__ fc2w, const float* __restrict__ fc2b,
    const float* __restrict__ fc3w, const float* __restrict__ fc3b,
    short* __restrict__ wT2, short* __restrict__ wT3,
    float2* __restrict__ ab1, float2* __restrict__ ab2, float2* __restrict__ ab3,
    float* __restrict__ qc)
{
    int tid = blockIdx.x * 256 + threadIdx.x;
    if (tid < 73728) {                       // 9*128*64
        int ic = tid & 63, oc = (tid >> 6) & 127, k = tid >> 13;
        wT2[tid] = (short)f2bfu(c2w[(oc * 64 + ic) * 9 + k]);
    }
    if (tid < 294912) {                      // 9*256*128
        int ic = tid & 127, oc = (tid >> 7) & 255, k = tid >> 15;
        wT3[tid] = (short)f2bfu(c3w[(oc * 128 + ic) * 9 + k]);
    }
    if (tid < 64) {
        float s = g1[tid] / sqrtf(v1[tid] + 1e-5f);
        ab1[tid] = make_float2(s, (c1b[tid] - m1[tid]) * s + b1[tid]);
    } else if (tid < 192) {
        int c = tid - 64;
        float s = g2[c] / sqrtf(v2[c] + 1e-5f);
        ab2[c] = make_float2(s, (c2b[c] - m2[c]) * s + b2[c]);
    } else if (tid < 448) {
        int c = tid - 192;
        float s = g3[c] / sqrtf(v3[c] + 1e-5f);
        ab3[c] = make_float2(s, (c3b[c] - m3[c]) * s + b3[c]);
    } else if (tid == 448) {
        float A0 = 0.f, A1 = 0.f, B0 = 0.f, B1 = 0.f;
        for (int k = 0; k < 128; ++k) {
            float f2 = fc2w[k], fb = fc2b[k];
            A0 += fc3w[k] * f2;        B0 += fc3w[k] * fb;
            A1 += fc3w[128 + k] * f2;  B1 += fc3w[128 + k] * fb;
        }
        qc[0] = A0; qc[1] = A1;
        qc[2] = B0 + fc3b[0]; qc[3] = B1 + fc3b[1];
        qc[4] = cosf(qp[1]);  qc[5] = fc1b[1];
    }
}

// ---------------- fused: conv1 -> conv2(MFMA) -> conv3(MFMA) -> tail. One block per image. ----------------
// LDS: smem holds conv2 input tile (33,024 B incl. OOB pad); conv3 tile ALIASES smem (re-zeroed
// between barriers after conv2's MFMA loop finishes reading). xt = padded 28x28 fp32 input.
// NOTE: __launch_bounds__(256, 2) — min-waves=3 caps regs at ~170/wave and SPILLS the 112-AGPR
// stage-B accumulator to scratch (measured: 2.37 GB HBM traffic, 2.2x slowdown). Keep at 2.
__global__ __launch_bounds__(256, 2) void fused_k(
    const float* __restrict__ x, const float* __restrict__ c1w,
    const float2* __restrict__ ab1, const float2* __restrict__ ab2,
    const float2* __restrict__ ab3,
    const short* __restrict__ wT2, const short* __restrict__ wT3,
    const float* __restrict__ fc1w, const float* __restrict__ qc,
    float* __restrict__ out)
{
    __shared__ short smem[16 * 16 * 64 + 128]; // conv2 tile [y][x][8 blk][8 ic] swizzled + pad (33,024 B)
    __shared__ float xt[30][32];               // padded 28x28 input at [1..28][1..28]      (3,840 B)
    __shared__ float red[4];

    int b = blockIdx.x, t = threadIdx.x;

    // ---- zero-init (padding must be 0) ----
    for (int i = t; i < 8256; i += 256) ((unsigned*)smem)[i] = 0u;
    for (int i = t; i < 960;  i += 256) ((float*)xt)[i] = 0.f;
    __syncthreads();

    // ---- stage A: load input, conv1 (packed fp32) + BN + ReLU + 2x2 pool -> smem (conv2 tile) ----
    for (int i = t; i < 784; i += 256) xt[i / 28 + 1][i % 28 + 1] = x[b * 784 + i];

    int ocg = t & 7;                         // 8 groups of 8 output channels
    float wr[8][9];
    float2 abr[8];
#pragma unroll
    for (int c = 0; c < 8; ++c) {
#pragma unroll
        for (int k = 0; k < 9; ++k) wr[c][k] = c1w[(ocg * 8 + c) * 9 + k];
        abr[c] = ab1[ocg * 8 + c];
    }
    __syncthreads();

    int posb = t >> 3;                       // 0..31
    for (int p = posb; p < 196; p += 32) {
        int py = p / 14, px = p % 14;
        int y0 = 2 * py, x0 = 2 * px;        // x0 even -> 8B-aligned v2f loads
        v2f rowv[4][2];
#pragma unroll
        for (int i = 0; i < 4; ++i) {
            rowv[i][0] = *(const v2f*)&xt[y0 + i][x0];
            rowv[i][1] = *(const v2f*)&xt[y0 + i][x0 + 2];
        }
        unsigned short ub[8];
#pragma unroll
        for (int c = 0; c < 8; ++c) {
            v2f a0 = {0.f, 0.f}, a1 = {0.f, 0.f};   // (out00,out01), (out10,out11)
#pragma unroll
            for (int ky = 0; ky < 3; ++ky) {
                float w0 = wr[c][ky * 3 + 0], w1 = wr[c][ky * 3 + 1], w2 = wr[c][ky * 3 + 2];
                v2f p00 = rowv[ky][0],     p01 = rowv[ky][1];
                v2f p10 = rowv[ky + 1][0], p11 = rowv[ky + 1][1];
                v2f q0; q0.x = p00.y; q0.y = p01.x;
                v2f q1; q1.x = p10.y; q1.y = p11.x;
                a0 += p00 * w0; a0 += q0 * w1; a0 += p01 * w2;
                a1 += p10 * w0; a1 += q1 * w1; a1 += p11 * w2;
            }
            float aa = abr[c].x, bb = abr[c].y;
            v2f r0 = a0 * aa + bb;
            v2f r1 = a1 * aa + bb;
            float v = fmaxf(fmaxf(fmaxf(r0.x, r0.y), fmaxf(r1.x, r1.y)), 0.f);
            ub[c] = f2bfu(v);
        }
        uint4 pk;
        pk.x = (unsigned)ub[0] | ((unsigned)ub[1] << 16);
        pk.y = (unsigned)ub[2] | ((unsigned)ub[3] << 16);
        pk.z = (unsigned)ub[4] | ((unsigned)ub[5] << 16);
        pk.w = (unsigned)ub[6] | ((unsigned)ub[7] << 16);
        int blk = ocg ^ ((px + 1) & 7);      // XOR swizzle by padded column
        *(uint4*)&smem[((((py + 1) * 16) + (px + 1)) * 8 + blk) * 8] = pk;
    }
    __syncthreads();

    // ---- stage B: conv2 (64->128) MFMA. Waves: (oc-half oh) x (pooled-col-half cb). ----
    int lane = t & 63, wid = t >> 6;
    int quad = lane >> 4, n16 = lane & 15;
    int dy = n16 >> 3, lx = n16 & 7;
    int cb = wid >> 1;                       // 0: output cols 1..8 ; 1: cols 9..16
    int oh = wid & 1;                        // oc half (64 ocs)

    {
        f32x4 acc[4][7];                     // [ml(16oc)][ry(pooled row)]
        f32x4 z = {0.f, 0.f, 0.f, 0.f};
#pragma unroll
        for (int ml = 0; ml < 4; ++ml)
#pragma unroll
            for (int ry = 0; ry < 7; ++ry) acc[ml][ry] = z;

#pragma unroll 1
        for (int kykx = 0; kykx < 9; ++kykx) {
            int ky = kykx / 3, kx = kykx - 3 * ky;
            int y0 = dy + ky;
            int xc = lx + kx + cb * 8;       // padded input col (garbage lanes lx>=6@cb=1 discarded)
            const short* aB = wT2 + (kykx * 128 + oh * 64 + n16) * 64 + quad * 8;
#pragma unroll
            for (int kk = 0; kk < 2; ++kk) {
                int blk = (kk * 4 + quad) ^ (xc & 7);
                const short* bp = &smem[((y0 * 16 + xc) * 8 + blk) * 8];
                s16x8 A[4];
#pragma unroll
                for (int ml = 0; ml < 4; ++ml)
                    A[ml] = *(const s16x8*)(aB + ml * 1024 + kk * 32);
#pragma unroll
                for (int ry = 0; ry < 7; ++ry) {
                    s16x8 B = *(const s16x8*)(bp + ry * 2048);   // immediate offsets
#pragma unroll
                    for (int ml = 0; ml < 4; ++ml)
                        acc[ml][ry] = __builtin_amdgcn_mfma_f32_16x16x32_bf16(A[ml], B, acc[ml][ry], 0, 0, 0);
                }
            }
        }

        __syncthreads();                     // all waves done reading conv2 tile
        for (int i = t; i < 4224; i += 256) ((unsigned*)smem)[i] = 0u;  // zero conv3 tile (alias)
        __syncthreads();

        // epilogue: affine -> pool (shfl 1,8) -> ReLU -> store into conv3 tile (swizzled)
        int m = lx >> 1;
        int xp = cb * 4 + m;
        bool keep = (dy == 0) && ((lx & 1) == 0) && (xp < 7);
#pragma unroll
        for (int ml = 0; ml < 4; ++ml) {
            int oc0 = oh * 64 + ml * 16 + quad * 4;
            float2 abv[4];
#pragma unroll
            for (int r = 0; r < 4; ++r) abv[r] = ab2[oc0 + r];
#pragma unroll
            for (int ry = 0; ry < 7; ++ry) {
                float pv[4];
#pragma unroll
                for (int r = 0; r < 4; ++r) {
                    float v = acc[ml][ry][r] * abv[r].x + abv[r].y;
                    v = fmaxf(v, __shfl_xor(v, 1));
                    v = fmaxf(v, __shfl_xor(v, 8));
                    pv[r] = fmaxf(v, 0.f);
                }
                if (keep) {
                    uint2 pk;
                    pk.x = (unsigned)f2bfu(pv[0]) | ((unsigned)f2bfu(pv[1]) << 16);
                    pk.y = (unsigned)f2bfu(pv[2]) | ((unsigned)f2bfu(pv[3]) << 16);
                    int blk3 = (oc0 >> 3) ^ (((xp + 1) & 7) << 1);
                    *(uint2*)&smem[(((ry + 1) * 8 + (xp + 1)) * 16 + blk3) * 8 + (oc0 & 7)] = pk;
                }
            }
        }
    }
    __syncthreads();

    // ---- stage C: conv3 (128->256) MFMA. Waves: (oc-half oh3) x (nt group nth). ----
    int oh3 = wid & 1;                       // oc half (128 ocs, 8 frags)
    int nth = wid >> 1;                      // 0: pooled rows {0,1} ; 1: {2}

    f32x4 acc3[8][2];
    {
        f32x4 z = {0.f, 0.f, 0.f, 0.f};
#pragma unroll
        for (int ml = 0; ml < 8; ++ml) { acc3[ml][0] = z; acc3[ml][1] = z; }
    }

    if (nth == 0) {
#pragma unroll 1
        for (int kykx = 0; kykx < 9; ++kykx) {
            int ky = kykx / 3, kx = kykx - 3 * ky;
            int y0 = dy + ky;
            int x0 = lx + kx;                // garbage lanes lx>=6 discarded
            const short* aB = wT3 + (kykx * 256 + oh3 * 128 + n16) * 128 + quad * 8;
#pragma unroll
            for (int kk = 0; kk < 4; ++kk) {
                int blk = (kk * 4 + quad) ^ ((x0 & 7) << 1);
                const short* bp = &smem[((y0 * 8 + x0) * 16 + blk) * 8];
                s16x8 B0 = *(const s16x8*)(bp);
                s16x8 B1 = *(const s16x8*)(bp + 2048);
#pragma unroll
                for (int ml = 0; ml < 8; ++ml) {
                    s16x8 A = *(const s16x8*)(aB + ml * 2048 + kk * 32);
                    acc3[ml][0] = __builtin_amdgcn_mfma_f32_16x16x32_bf16(A, B0, acc3[ml][0], 0, 0, 0);
                    acc3[ml][1] = __builtin_amdgcn_mfma_f32_16x16x32_bf16(A, B1, acc3[ml][1], 0, 0, 0);
                }
            }
        }
    } else {
#pragma unroll 1
        for (int kykx = 0; kykx < 9; ++kykx) {
            int ky = kykx / 3, kx = kykx - 3 * ky;
            int y0 = dy + ky;
            int x0 = lx + kx;
            const short* aB = wT3 + (kykx * 256 + oh3 * 128 + n16) * 128 + quad * 8;
#pragma unroll
            for (int kk = 0; kk < 4; ++kk) {
                int blk = (kk * 4 + quad) ^ ((x0 & 7) << 1);
                const short* bp = &smem[((y0 * 8 + x0) * 16 + blk) * 8 + 4096];  // rows y_in = 4+..
                s16x8 B0 = *(const s16x8*)(bp);
#pragma unroll
                for (int ml = 0; ml < 8; ++ml) {
                    s16x8 A = *(const s16x8*)(aB + ml * 2048 + kk * 32);
                    acc3[ml][0] = __builtin_amdgcn_mfma_f32_16x16x32_bf16(A, B0, acc3[ml][0], 0, 0, 0);
                }
            }
        }
    }

    // epilogue: affine -> pool -> relu -> dot with fc1_w row 1
    float vacc = 0.f;
    {
        int m = lx >> 1;
        bool keep = (dy == 0) && ((lx & 1) == 0) && (m < 3);
        const float* fc1w1 = fc1w + 2304;    // row 1 (only row that matters)
        int ntCount = (nth == 0) ? 2 : 1;
#pragma unroll
        for (int ml = 0; ml < 8; ++ml) {
            int oc0 = oh3 * 128 + ml * 16 + quad * 4;
            float2 abv[4];
#pragma unroll
            for (int r = 0; r < 4; ++r) abv[r] = ab3[oc0 + r];
            for (int ntl = 0; ntl < ntCount; ++ntl) {
                int nt = nth * 2 + ntl;      // pooled row
#pragma unroll
                for (int r = 0; r < 4; ++r) {
                    float v = acc3[ml][ntl][r] * abv[r].x + abv[r].y;
                    v = fmaxf(v, __shfl_xor(v, 1));
                    v = fmaxf(v, __shfl_xor(v, 8));
                    v = fmaxf(v, 0.f);
                    if (keep) vacc += v * fc1w1[(oc0 + r) * 9 + nt * 3 + m];
                }
            }
        }
    }
#pragma unroll
    for (int s = 1; s < 64; s <<= 1) vacc += __shfl_xor(vacc, s);
    if (lane == 0) red[wid] = vacc;
    __syncthreads();
    if (t == 0) {
        float v = red[0] + red[1] + red[2] + red[3] + qc[5];
        // quantum circuit closed form: <Z0 Z1> = cos(h[:,1]) * cos(qp[1])
        float q = cosf(v) * qc[4];
        float l0 = q * qc[0] + qc[2];
        float l1 = q * qc[1] + qc[3];
        float mx = fmaxf(l0, l1);
        float lse = mx + logf(__expf(l0 - mx) + __expf(l1 - mx));
        out[b * 2 + 0] = l0 - lse;
        out[b * 2 + 1] = l1 - lse;
    }
}

extern "C" void kernel_launch(void* const* d_in, const int* in_sizes, int n_in,
                              void* d_out, int out_size, void* d_ws, size_t ws_size,
                              hipStream_t stream)
{
    const float* x    = (const float*)d_in[0];
    const float* c1w  = (const float*)d_in[1];
    const float* c1b  = (const float*)d_in[2];
    const float* c2w  = (const float*)d_in[3];
    const float* c2b  = (const float*)d_in[4];
    const float* c3w  = (const float*)d_in[5];
    const float* c3b  = (const float*)d_in[6];
    const float* g1   = (const float*)d_in[7];
    const float* b1   = (const float*)d_in[8];
    const float* m1   = (const float*)d_in[9];
    const float* v1   = (const float*)d_in[10];
    const float* g2   = (const float*)d_in[11];
    const float* b2   = (const float*)d_in[12];
    const float* m2   = (const float*)d_in[13];
    const float* v2   = (const float*)d_in[14];
    const float* g3   = (const float*)d_in[15];
    const float* b3   = (const float*)d_in[16];
    const float* m3   = (const float*)d_in[17];
    const float* v3   = (const float*)d_in[18];
    const float* fc1w = (const float*)d_in[19];
    const float* fc1b = (const float*)d_in[20];
    const float* qp   = (const float*)d_in[21];
    const float* fc2w = (const float*)d_in[22];
    const float* fc2b = (const float*)d_in[23];
    const float* fc3w = (const float*)d_in[24];
    const float* fc3b = (const float*)d_in[25];
    float* out = (float*)d_out;
    char* ws = (char*)d_ws;

    short*  wT2 = (short*)(ws + OFF_W2);
    short*  wT3 = (short*)(ws + OFF_W3);
    float2* ab1 = (float2*)(ws + OFF_AB1);
    float2* ab2 = (float2*)(ws + OFF_AB2);
    float2* ab3 = (float2*)(ws + OFF_AB3);
    float*  qc  = (float*)(ws + OFF_Q);

    int B = in_sizes[0] / 784;               // 8192

    prep_k<<<1152, 256, 0, stream>>>(c2w, c3w, c1b, g1, b1, m1, v1,
                                     c2b, g2, b2, m2, v2, c3b, g3, b3, m3, v3,
                                     fc1b, qp, fc2w, fc2b, fc3w, fc3b,
                                     wT2, wT3, ab1, ab2, ab3, qc);
    fused_k<<<B, 256, 0, stream>>>(x, c1w, ab1, ab2, ab3, wT2, wT3, fc1w, qc, out);
}

// Round 5
// 1039.724 us; speedup vs baseline: 2.1339x; 1.7038x over previous
//
#include <hip/hip_runtime.h>
#include <hip/hip_bf16.h>
#include <math.h>

typedef float f32x4 __attribute__((ext_vector_type(4)));
typedef short s16x8 __attribute__((ext_vector_type(8)));
typedef float v2f   __attribute__((ext_vector_type(2)));

// ---- workspace layout (bytes) ---- total < 1 MB
static const long long OFF_W2  = 0LL;        // bf16 [9][128][64]  = 147,456 B
static const long long OFF_W3  = 147456LL;   // bf16 [9][256][128] = 589,824 B
static const long long OFF_AB1 = 737280LL;   // float2 [64]
static const long long OFF_AB2 = 737792LL;   // float2 [128]
static const long long OFF_AB3 = 738816LL;   // float2 [256]
static const long long OFF_Q   = 740864LL;   // float  [8]

__device__ inline unsigned short f2bfu(float f) {
    __hip_bfloat16 h = __float2bfloat16(f);
    unsigned short u;
    __builtin_memcpy(&u, &h, 2);
    return u;
}

// ---------------- prep: weight transpose to [kykx][oc][ic] bf16 + BN folding + fc fold ----------------
__global__ __launch_bounds__(256) void prep_k(
    const float* __restrict__ c2w, const float* __restrict__ c3w,
    const float* __restrict__ c1b, const float* __restrict__ g1, const float* __restrict__ b1,
    const float* __restrict__ m1, const float* __restrict__ v1,
    const float* __restrict__ c2b, const float* __restrict__ g2, const float* __restrict__ b2,
    const float* __restrict__ m2, const float* __restrict__ v2,
    const float* __restrict__ c3b, const float* __restrict__ g3, const float* __restrict__ b3,
    const float* __restrict__ m3, const float* __restrict__ v3,
    const float* __restrict__ fc1b, const float* __restrict__ qp,
    const float* __restrict__ fc2w, const float* __restrict__ fc2b,
    const float* __restrict__ fc3w, const float* __restrict__ fc3b,
    short* __restrict__ wT2, short* __restrict__ wT3,
    float2* __restrict__ ab1, float2* __restrict__ ab2, float2* __restrict__ ab3,
    float* __restrict__ qc)
{
    int tid = blockIdx.x * 256 + threadIdx.x;
    if (tid < 73728) {                       // 9*128*64
        int ic = tid & 63, oc = (tid >> 6) & 127, k = tid >> 13;
        wT2[tid] = (short)f2bfu(c2w[(oc * 64 + ic) * 9 + k]);
    }
    if (tid < 294912) {                      // 9*256*128
        int ic = tid & 127, oc = (tid >> 7) & 255, k = tid >> 15;
        wT3[tid] = (short)f2bfu(c3w[(oc * 128 + ic) * 9 + k]);
    }
    if (tid < 64) {
        float s = g1[tid] / sqrtf(v1[tid] + 1e-5f);
        ab1[tid] = make_float2(s, (c1b[tid] - m1[tid]) * s + b1[tid]);
    } else if (tid < 192) {
        int c = tid - 64;
        float s = g2[c] / sqrtf(v2[c] + 1e-5f);
        ab2[c] = make_float2(s, (c2b[c] - m2[c]) * s + b2[c]);
    } else if (tid < 448) {
        int c = tid - 192;
        float s = g3[c] / sqrtf(v3[c] + 1e-5f);
        ab3[c] = make_float2(s, (c3b[c] - m3[c]) * s + b3[c]);
    } else if (tid == 448) {
        float A0 = 0.f, A1 = 0.f, B0 = 0.f, B1 = 0.f;
        for (int k = 0; k < 128; ++k) {
            float f2 = fc2w[k], fb = fc2b[k];
            A0 += fc3w[k] * f2;        B0 += fc3w[k] * fb;
            A1 += fc3w[128 + k] * f2;  B1 += fc3w[128 + k] * fb;
        }
        qc[0] = A0; qc[1] = A1;
        qc[2] = B0 + fc3b[0]; qc[3] = B1 + fc3b[1];
        qc[4] = cosf(qp[1]);  qc[5] = fc1b[1];
    }
}

// ---------------- fused: conv1 -> conv2(MFMA) -> conv3(MFMA) -> tail. One block per image. ----------------
// Register budget note (unified VGPR+AGPR, 256/wave at launch_bounds(256,2)):
//   stage A peak ~76 VGPR (4-oc passes), stage B accs 112 AGPR, stage C accs 48 AGPR.
//   Round-4's 8-oc conv1 (72 w-regs) + 64-acc stage C spilled (646 MB scratch writes). Keep shapes lean.
__global__ __launch_bounds__(256, 2) void fused_k(
    const float* __restrict__ x, const float* __restrict__ c1w,
    const float2* __restrict__ ab1, const float2* __restrict__ ab2,
    const float2* __restrict__ ab3,
    const short* __restrict__ wT2, const short* __restrict__ wT3,
    const float* __restrict__ fc1w, const float* __restrict__ qc,
    float* __restrict__ out)
{
    __shared__ short smem[16 * 16 * 64 + 128]; // conv2 tile [y][x][8 blk][8 ic] swizzled + pad (33,024 B)
    __shared__ float xt[30][32];               // padded 28x28 input at [1..28][1..28]      (3,840 B)
    __shared__ float red[4];

    int b = blockIdx.x, t = threadIdx.x;

    // ---- zero-init (padding must be 0) ----
    for (int i = t; i < 8256; i += 256) ((unsigned*)smem)[i] = 0u;
    for (int i = t; i < 960;  i += 256) ((float*)xt)[i] = 0.f;
    __syncthreads();

    // ---- stage A: load input, conv1 (packed fp32) + BN + ReLU + 2x2 pool -> smem (conv2 tile) ----
    for (int i = t; i < 784; i += 256) xt[i / 28 + 1][i % 28 + 1] = x[b * 784 + i];
    __syncthreads();

    int ocg = t & 7;                         // 8 groups of 8 output channels; 2 passes of 4 ocs
    int posb = t >> 3;                       // 0..31
#pragma unroll 1
    for (int pass = 0; pass < 2; ++pass) {
        int oc0 = ocg * 8 + pass * 4;
        float wr[4][9];
        float2 abr[4];
#pragma unroll
        for (int c = 0; c < 4; ++c) {
#pragma unroll
            for (int k = 0; k < 9; ++k) wr[c][k] = c1w[(oc0 + c) * 9 + k];
            abr[c] = ab1[oc0 + c];
        }
        for (int p = posb; p < 196; p += 32) {
            int py = p / 14, px = p % 14;
            int y0 = 2 * py, x0 = 2 * px;    // x0 even -> 8B-aligned v2f loads
            v2f rowv[4][2];
#pragma unroll
            for (int i = 0; i < 4; ++i) {
                rowv[i][0] = *(const v2f*)&xt[y0 + i][x0];
                rowv[i][1] = *(const v2f*)&xt[y0 + i][x0 + 2];
            }
            unsigned short ub[4];
#pragma unroll
            for (int c = 0; c < 4; ++c) {
                v2f a0 = {0.f, 0.f}, a1 = {0.f, 0.f};   // (out00,out01), (out10,out11)
#pragma unroll
                for (int ky = 0; ky < 3; ++ky) {
                    float w0 = wr[c][ky * 3 + 0], w1 = wr[c][ky * 3 + 1], w2 = wr[c][ky * 3 + 2];
                    v2f p00 = rowv[ky][0],     p01 = rowv[ky][1];
                    v2f p10 = rowv[ky + 1][0], p11 = rowv[ky + 1][1];
                    v2f q0; q0.x = p00.y; q0.y = p01.x;
                    v2f q1; q1.x = p10.y; q1.y = p11.x;
                    a0 += p00 * w0; a0 += q0 * w1; a0 += p01 * w2;
                    a1 += p10 * w0; a1 += q1 * w1; a1 += p11 * w2;
                }
                float aa = abr[c].x, bb = abr[c].y;
                v2f r0 = a0 * aa + bb;
                v2f r1 = a1 * aa + bb;
                float v = fmaxf(fmaxf(fmaxf(r0.x, r0.y), fmaxf(r1.x, r1.y)), 0.f);
                ub[c] = f2bfu(v);
            }
            uint2 pk;
            pk.x = (unsigned)ub[0] | ((unsigned)ub[1] << 16);
            pk.y = (unsigned)ub[2] | ((unsigned)ub[3] << 16);
            int blk = ocg ^ ((px + 1) & 7);  // XOR swizzle by padded column (8-ic block index)
            *(uint2*)&smem[((((py + 1) * 16) + (px + 1)) * 8 + blk) * 8 + pass * 4] = pk;
        }
    }
    __syncthreads();

    // ---- stage B: conv2 (64->128) MFMA. Waves: (oc-half oh) x (pooled-col-half cb). ----
    int lane = t & 63, wid = t >> 6;
    int quad = lane >> 4, n16 = lane & 15;
    int dy = n16 >> 3, lx = n16 & 7;
    int cb = wid >> 1;                       // 0: output cols 1..8 ; 1: cols 9..16
    int oh = wid & 1;                        // oc half (64 ocs)

    {
        f32x4 acc[4][7];                     // [ml(16oc)][ry(pooled row)]  = 112 AGPR
        f32x4 z = {0.f, 0.f, 0.f, 0.f};
#pragma unroll
        for (int ml = 0; ml < 4; ++ml)
#pragma unroll
            for (int ry = 0; ry < 7; ++ry) acc[ml][ry] = z;

#pragma unroll 1
        for (int kykx = 0; kykx < 9; ++kykx) {
            int ky = kykx / 3, kx = kykx - 3 * ky;
            int y0 = dy + ky;
            int xc = lx + kx + cb * 8;       // padded input col (garbage lanes lx>=6@cb=1 discarded)
            const short* aB = wT2 + (kykx * 128 + oh * 64 + n16) * 64 + quad * 8;
#pragma unroll
            for (int kk = 0; kk < 2; ++kk) {
                int blk = (kk * 4 + quad) ^ (xc & 7);
                const short* bp = &smem[((y0 * 16 + xc) * 8 + blk) * 8];
                s16x8 A[4];
#pragma unroll
                for (int ml = 0; ml < 4; ++ml)
                    A[ml] = *(const s16x8*)(aB + ml * 1024 + kk * 32);
#pragma unroll
                for (int ry = 0; ry < 7; ++ry) {
                    s16x8 B = *(const s16x8*)(bp + ry * 2048);   // immediate offsets
#pragma unroll
                    for (int ml = 0; ml < 4; ++ml)
                        acc[ml][ry] = __builtin_amdgcn_mfma_f32_16x16x32_bf16(A[ml], B, acc[ml][ry], 0, 0, 0);
                }
            }
        }

        __syncthreads();                     // all waves done reading conv2 tile
        for (int i = t; i < 4224; i += 256) ((unsigned*)smem)[i] = 0u;  // zero conv3 tile (alias)
        __syncthreads();

        // epilogue: affine -> pool (shfl 1,8) -> ReLU -> store into conv3 tile (swizzled)
        int m = lx >> 1;
        int xp = cb * 4 + m;
        bool keep = (dy == 0) && ((lx & 1) == 0) && (xp < 7);
#pragma unroll
        for (int ml = 0; ml < 4; ++ml) {
            int oc0 = oh * 64 + ml * 16 + quad * 4;
            float2 abv[4];
#pragma unroll
            for (int r = 0; r < 4; ++r) abv[r] = ab2[oc0 + r];
#pragma unroll
            for (int ry = 0; ry < 7; ++ry) {
                float pv[4];
#pragma unroll
                for (int r = 0; r < 4; ++r) {
                    float v = acc[ml][ry][r] * abv[r].x + abv[r].y;
                    v = fmaxf(v, __shfl_xor(v, 1));
                    v = fmaxf(v, __shfl_xor(v, 8));
                    pv[r] = fmaxf(v, 0.f);
                }
                if (keep) {
                    uint2 pk;
                    pk.x = (unsigned)f2bfu(pv[0]) | ((unsigned)f2bfu(pv[1]) << 16);
                    pk.y = (unsigned)f2bfu(pv[2]) | ((unsigned)f2bfu(pv[3]) << 16);
                    int blk3 = (oc0 >> 3) ^ (((xp + 1) & 7) << 1);
                    *(uint2*)&smem[(((ry + 1) * 8 + (xp + 1)) * 16 + blk3) * 8 + (oc0 & 7)] = pk;
                }
            }
        }
    }
    __syncthreads();

    // ---- stage C: conv3 (128->256) MFMA. Waves: oc-quarter each, all 3 pooled rows. 48 AGPR. ----
    int oq = wid;                            // oc quarter (64 ocs, 4 frags of 16)

    f32x4 acc3[4][3];
    {
        f32x4 z = {0.f, 0.f, 0.f, 0.f};
#pragma unroll
        for (int ml = 0; ml < 4; ++ml)
#pragma unroll
            for (int nt = 0; nt < 3; ++nt) acc3[ml][nt] = z;
    }

#pragma unroll 1
    for (int kykx = 0; kykx < 9; ++kykx) {
        int ky = kykx / 3, kx = kykx - 3 * ky;
        int y0 = dy + ky;
        int x0 = lx + kx;                    // garbage lanes lx>=6 discarded
        const short* aB = wT3 + (kykx * 256 + oq * 64 + n16) * 128 + quad * 8;
#pragma unroll
        for (int kk = 0; kk < 4; ++kk) {
            int blk = (kk * 4 + quad) ^ ((x0 & 7) << 1);
            const short* bp = &smem[((y0 * 8 + x0) * 16 + blk) * 8];
            s16x8 B0 = *(const s16x8*)(bp);            // pooled row 0 (y_in = y0)
            s16x8 B1 = *(const s16x8*)(bp + 2048);     // pooled row 1 (y_in = y0+2)
            s16x8 B2 = *(const s16x8*)(bp + 4096);     // pooled row 2 (y_in = y0+4)
#pragma unroll
            for (int ml = 0; ml < 4; ++ml) {
                s16x8 A = *(const s16x8*)(aB + ml * 2048 + kk * 32);
                acc3[ml][0] = __builtin_amdgcn_mfma_f32_16x16x32_bf16(A, B0, acc3[ml][0], 0, 0, 0);
                acc3[ml][1] = __builtin_amdgcn_mfma_f32_16x16x32_bf16(A, B1, acc3[ml][1], 0, 0, 0);
                acc3[ml][2] = __builtin_amdgcn_mfma_f32_16x16x32_bf16(A, B2, acc3[ml][2], 0, 0, 0);
            }
        }
    }

    // epilogue: affine -> pool -> relu -> dot with fc1_w row 1
    float vacc = 0.f;
    {
        int m = lx >> 1;
        bool keep = (dy == 0) && ((lx & 1) == 0) && (m < 3);
        const float* fc1w1 = fc1w + 2304;    // row 1 (only row that matters)
#pragma unroll
        for (int ml = 0; ml < 4; ++ml) {
            int oc0 = oq * 64 + ml * 16 + quad * 4;
            float2 abv[4];
#pragma unroll
            for (int r = 0; r < 4; ++r) abv[r] = ab3[oc0 + r];
#pragma unroll
            for (int nt = 0; nt < 3; ++nt) {
#pragma unroll
                for (int r = 0; r < 4; ++r) {
                    float v = acc3[ml][nt][r] * abv[r].x + abv[r].y;
                    v = fmaxf(v, __shfl_xor(v, 1));
                    v = fmaxf(v, __shfl_xor(v, 8));
                    v = fmaxf(v, 0.f);
                    if (keep) vacc += v * fc1w1[(oc0 + r) * 9 + nt * 3 + m];
                }
            }
        }
    }
#pragma unroll
    for (int s = 1; s < 64; s <<= 1) vacc += __shfl_xor(vacc, s);
    if (lane == 0) red[wid] = vacc;
    __syncthreads();
    if (t == 0) {
        float v = red[0] + red[1] + red[2] + red[3] + qc[5];
        // quantum circuit closed form: <Z0 Z1> = cos(h[:,1]) * cos(qp[1])
        float q = cosf(v) * qc[4];
        float l0 = q * qc[0] + qc[2];
        float l1 = q * qc[1] + qc[3];
        float mx = fmaxf(l0, l1);
        float lse = mx + logf(__expf(l0 - mx) + __expf(l1 - mx));
        out[b * 2 + 0] = l0 - lse;
        out[b * 2 + 1] = l1 - lse;
    }
}

extern "C" void kernel_launch(void* const* d_in, const int* in_sizes, int n_in,
                              void* d_out, int out_size, void* d_ws, size_t ws_size,
                              hipStream_t stream)
{
    const float* x    = (const float*)d_in[0];
    const float* c1w  = (const float*)d_in[1];
    const float* c1b  = (const float*)d_in[2];
    const float* c2w  = (const float*)d_in[3];
    const float* c2b  = (const float*)d_in[4];
    const float* c3w  = (const float*)d_in[5];
    const float* c3b  = (const float*)d_in[6];
    const float* g1   = (const float*)d_in[7];
    const float* b1   = (const float*)d_in[8];
    const float* m1   = (const float*)d_in[9];
    const float* v1   = (const float*)d_in[10];
    const float* g2   = (const float*)d_in[11];
    const float* b2   = (const float*)d_in[12];
    const float* m2   = (const float*)d_in[13];
    const float* v2   = (const float*)d_in[14];
    const float* g3   = (const float*)d_in[15];
    const float* b3   = (const float*)d_in[16];
    const float* m3   = (const float*)d_in[17];
    const float* v3   = (const float*)d_in[18];
    const float* fc1w = (const float*)d_in[19];
    const float* fc1b = (const float*)d_in[20];
    const float* qp   = (const float*)d_in[21];
    const float* fc2w = (const float*)d_in[22];
    const float* fc2b = (const float*)d_in[23];
    const float* fc3w = (const float*)d_in[24];
    const float* fc3b = (const float*)d_in[25];
    float* out = (float*)d_out;
    char* ws = (char*)d_ws;

    short*  wT2 = (short*)(ws + OFF_W2);
    short*  wT3 = (short*)(ws + OFF_W3);
    float2* ab1 = (float2*)(ws + OFF_AB1);
    float2* ab2 = (float2*)(ws + OFF_AB2);
    float2* ab3 = (float2*)(ws + OFF_AB3);
    float*  qc  = (float*)(ws + OFF_Q);

    int B = in_sizes[0] / 784;               // 8192

    prep_k<<<1152, 256, 0, stream>>>(c2w, c3w, c1b, g1, b1, m1, v1,
                                     c2b, g2, b2, m2, v2, c3b, g3, b3, m3, v3,
                                     fc1b, qp, fc2w, fc2b, fc3w, fc3b,
                                     wT2, wT3, ab1, ab2, ab3, qc);
    fused_k<<<B, 256, 0, stream>>>(x, c1w, ab1, ab2, ab3, wT2, wT3, fc1w, qc, out);
}